// Round 1
// baseline (323.217 us; speedup 1.0000x reference)
//
#include <hip/hip_runtime.h>

typedef unsigned short ushort_t;
typedef __attribute__((ext_vector_type(8))) short short8;
typedef __attribute__((ext_vector_type(4))) float floatx4;
typedef __attribute__((ext_vector_type(4))) unsigned short ushort4v;

#define DD 256
#define LL 3
#define GG 4
#define KK 128
#define UU 64
#define OUTN 10
#define HSTRIDE 264   // 256 + 8 bf16 pad: breaks LDS bank conflicts (row stride 528B -> 2-way, free)

__device__ __forceinline__ ushort_t f2bf(float f) {
  unsigned u = __builtin_bit_cast(unsigned, f);
  u = (u + 0x7FFFu + ((u >> 16) & 1u)) >> 16;  // RNE; inputs finite
  return (ushort_t)u;
}

__device__ __forceinline__ float fast_tanh(float x) {
  float a = fabsf(x);
  float e = __expf(2.0f * a);                      // v_exp_f32 path
  float r = 1.0f - 2.0f * __builtin_amdgcn_rcpf(e + 1.0f);
  return copysignf(r, x);                          // large |x| -> e=inf -> r=1
}

// Build AT[l][n][k] = sum_{j: idx[l,g,j]==k} W[l,g,j,u]  (n = g*64+u), bf16,
// and WoT[n][k] = W_out[k][n] (n<10, else 0) padded to 16 rows, bf16.
__global__ void prep_kernel(const int* __restrict__ idx, const float* __restrict__ W,
                            const float* __restrict__ Wout,
                            ushort_t* __restrict__ AT, ushort_t* __restrict__ WoT) {
  int e = blockIdx.x * 256 + threadIdx.x;
  if (e < LL * DD * DD) {
    int l = e >> 16;
    int r = e & 65535;
    int n = r >> 8;
    int k = r & 255;
    int g = n >> 6;
    int u = n & 63;
    const int* ip = idx + (l * GG + g) * KK;
    const float* wp = W + ((size_t)(l * GG + g) * KK) * UU + u;
    float s = 0.f;
#pragma unroll 4
    for (int j = 0; j < KK; j++) {
      if (ip[j] == k) s += wp[j * UU];
    }
    AT[e] = f2bf(s);
  } else {
    int e2 = e - LL * DD * DD;
    if (e2 < 16 * DD) {
      int n = e2 >> 8;
      int k = e2 & 255;
      WoT[e2] = (n < OUTN) ? f2bf(Wout[k * OUTN + n]) : (ushort_t)0;
    }
  }
}

__global__ __launch_bounds__(256) void fused_kernel(
    const float* __restrict__ x, const float* __restrict__ bias,
    const float* __restrict__ bout, const ushort_t* __restrict__ AT,
    const ushort_t* __restrict__ WoT, float* __restrict__ out) {
  __shared__ ushort_t hbuf[64 * HSTRIDE];  // 33792 B

  const int tid  = threadIdx.x;
  const int wave = tid >> 6;     // wave == group g (4 waves, G=4)
  const int lane = tid & 63;
  const int quad = lane >> 4;
  const int l16  = lane & 15;
  const long row0 = (long)blockIdx.x * 64;

  // ---- stage x tile (64 x 256 fp32) -> bf16 LDS, coalesced float4 loads ----
  const float4* xv = (const float4*)(x + row0 * DD);
#pragma unroll
  for (int i = 0; i < 16; i++) {
    int f  = tid + i * 256;      // 0..4095 float4s
    int r  = f >> 6;             // row (64 float4 per row)
    int c4 = f & 63;
    float4 v = xv[r * 64 + c4];
    ushort4v uv;
    uv.x = f2bf(v.x); uv.y = f2bf(v.y); uv.z = f2bf(v.z); uv.w = f2bf(v.w);
    *(ushort4v*)&hbuf[r * HSTRIDE + c4 * 4] = uv;   // 8B aligned (stride 528B, col mult of 8B)
  }
  __syncthreads();

  // ---- 3 levels: h = tanh(h @ A_l + b_l), all MFMA 16x16x32 bf16 ----
  const floatx4 zero = {0.f, 0.f, 0.f, 0.f};
  for (int l = 0; l < 3; l++) {
    const ushort_t* A = AT + l * (DD * DD);
    floatx4 acc[4][4];
#pragma unroll
    for (int mt = 0; mt < 4; mt++)
#pragma unroll
      for (int nt = 0; nt < 4; nt++) acc[mt][nt] = zero;

#pragma unroll
    for (int ks = 0; ks < 8; ks++) {
      const int kb = ks * 32 + quad * 8;
      short8 af[4], bfr[4];
#pragma unroll
      for (int mt = 0; mt < 4; mt++)   // A-frag: h[m=l16][k..k+7], ds_read_b128, 16B aligned
        af[mt] = *(const short8*)&hbuf[(mt * 16 + l16) * HSTRIDE + kb];
#pragma unroll
      for (int nt = 0; nt < 4; nt++)   // B-frag: AT[n=l16][k..k+7], global 16B (L2-resident)
        bfr[nt] = *(const short8*)&A[(wave * 64 + nt * 16 + l16) * 256 + kb];
#pragma unroll
      for (int mt = 0; mt < 4; mt++)
#pragma unroll
        for (int nt = 0; nt < 4; nt++)
          acc[mt][nt] = __builtin_amdgcn_mfma_f32_16x16x32_bf16(af[mt], bfr[nt], acc[mt][nt], 0, 0, 0);
    }
    __syncthreads();  // all reads of hbuf done (acc complete) before overwrite

    // epilogue: bias + tanh -> bf16 back into hbuf. C/D layout: col=lane&15, row=quad*4+reg
#pragma unroll
    for (int nt = 0; nt < 4; nt++) {
      const int u  = nt * 16 + l16;
      const float bv = bias[(l * GG + wave) * UU + u];
#pragma unroll
      for (int mt = 0; mt < 4; mt++)
#pragma unroll
        for (int r = 0; r < 4; r++) {
          float z = acc[mt][nt][r] + bv;
          hbuf[(mt * 16 + quad * 4 + r) * HSTRIDE + wave * 64 + u] = f2bf(fast_tanh(z));
        }
    }
    __syncthreads();
  }

  // ---- final: out = h3 @ W_out + b_out, one 16-row M-tile per wave, N padded to 16 ----
  floatx4 accf = zero;
#pragma unroll
  for (int ks = 0; ks < 8; ks++) {
    const int kb = ks * 32 + quad * 8;
    short8 af  = *(const short8*)&hbuf[(wave * 16 + l16) * HSTRIDE + kb];
    short8 bfr = *(const short8*)&WoT[l16 * 256 + kb];
    accf = __builtin_amdgcn_mfma_f32_16x16x32_bf16(af, bfr, accf, 0, 0, 0);
  }
  if (l16 < OUTN) {
    const float bo = bout[l16];
#pragma unroll
    for (int r = 0; r < 4; r++) {
      int row = wave * 16 + quad * 4 + r;
      out[(row0 + row) * OUTN + l16] = accf[r] + bo;
    }
  }
}

extern "C" void kernel_launch(void* const* d_in, const int* in_sizes, int n_in,
                              void* d_out, int out_size, void* d_ws, size_t ws_size,
                              hipStream_t stream) {
  const float* x    = (const float*)d_in[0];   // (131072, 256) fp32
  const int*   idx  = (const int*)d_in[1];     // (3, 4, 128) int32
  const float* W    = (const float*)d_in[2];   // (3, 4, 128, 64) fp32
  const float* b    = (const float*)d_in[3];   // (3, 4, 64) fp32
  const float* Wout = (const float*)d_in[4];   // (256, 10) fp32
  const float* bout = (const float*)d_in[5];   // (10,) fp32
  float* out = (float*)d_out;                  // (131072, 10) fp32

  ushort_t* AT  = (ushort_t*)d_ws;             // 3*256*256 bf16 = 393216 B
  ushort_t* WoT = AT + LL * DD * DD;           // 16*256 bf16 = 8192 B

  // 196608 AT elems + 4096 WoT elems = 200704 = 784 * 256
  prep_kernel<<<784, 256, 0, stream>>>(idx, W, Wout, AT, WoT);
  fused_kernel<<<2048, 256, 0, stream>>>(x, b, bout, AT, WoT, out);
}

// Round 2
// 297.995 us; speedup vs baseline: 1.0846x; 1.0846x over previous
//
#include <hip/hip_runtime.h>

typedef unsigned short ushort_t;
typedef __attribute__((ext_vector_type(8))) short short8;
typedef __attribute__((ext_vector_type(4))) float floatx4;
typedef __attribute__((ext_vector_type(4))) unsigned short ushort4v;

#define DD 256
#define LL 3
#define GG 4
#define KK 128
#define UU 64
#define OUTN 10
#define HSTRIDE 264   // 256 + 8 bf16 pad

__device__ __forceinline__ ushort_t f2bf(float f) {
  unsigned u = __builtin_bit_cast(unsigned, f);
  u = (u + 0x7FFFu + ((u >> 16) & 1u)) >> 16;  // RNE; inputs finite
  return (ushort_t)u;
}

// tanh(x) = 1 - 2/(e^{2x}+1); branch-free, exact at +/-inf overflow
__device__ __forceinline__ float fast_tanh(float x) {
  float e = __builtin_amdgcn_exp2f(x * 2.885390081777927f);  // e^(2x)
  return __builtin_fmaf(-2.0f, __builtin_amdgcn_rcpf(e + 1.0f), 1.0f);
}

// AT[l][n][k] = sum_{j: idx[l,g,j]==k} W[l,g,j,u]  (n = g*64+u), bf16.
// WoT[n][k] = W_out[k][n] (n<10 else 0), 16x256 bf16.
__global__ __launch_bounds__(256) void prep_kernel(
    const int* __restrict__ idx, const float* __restrict__ W,
    const float* __restrict__ Wout, ushort_t* __restrict__ AT,
    ushort_t* __restrict__ WoT) {
  int b = blockIdx.x;
  int t = threadIdx.x;
  if (b < LL * DD) {                       // one block per (l, n)
    int l = b >> 8, n = b & 255, g = n >> 6, u = n & 63;
    __shared__ int sidx[KK];
    __shared__ float sw[KK];
    if (t < KK) {
      sidx[t] = idx[(l * GG + g) * KK + t];
      sw[t]   = W[((size_t)((l * GG + g) * KK + t)) * UU + u];
    }
    __syncthreads();
    float s = 0.f;
#pragma unroll 8
    for (int j = 0; j < KK; j++) s += (sidx[j] == t) ? sw[j] : 0.f;
    AT[(b << 8) | t] = f2bf(s);
  } else {
    int e2 = (b - LL * DD) * 256 + t;      // 16*256 WoT elements
    int n = e2 >> 8, k = e2 & 255;
    WoT[e2] = (n < OUTN) ? f2bf(Wout[k * OUTN + n]) : (ushort_t)0;
  }
}

__global__ __launch_bounds__(256) void fused_kernel(
    const float* __restrict__ x, const float* __restrict__ bias,
    const float* __restrict__ bout, const ushort_t* __restrict__ AT,
    const ushort_t* __restrict__ WoT, float* __restrict__ out) {
  __shared__ ushort_t hbuf[64 * HSTRIDE];  // 33792 B

  const int tid  = threadIdx.x;
  const int wave = tid >> 6;     // wave == group g
  const int lane = tid & 63;
  const int quad = lane >> 4;
  const int l16  = lane & 15;
  const long row0 = (long)blockIdx.x * 64;

  // ---- stage x tile (64 x 256 fp32) -> bf16 LDS ----
  const float4* xv = (const float4*)(x + row0 * DD);
#pragma unroll
  for (int i = 0; i < 16; i++) {
    int f  = tid + i * 256;
    int r  = f >> 6;
    int c4 = f & 63;
    float4 v = xv[r * 64 + c4];
    ushort4v uv;
    uv.x = f2bf(v.x); uv.y = f2bf(v.y); uv.z = f2bf(v.z); uv.w = f2bf(v.w);
    *(ushort4v*)&hbuf[r * HSTRIDE + c4 * 4] = uv;
  }
  __syncthreads();

  const floatx4 zero = {0.f, 0.f, 0.f, 0.f};

  // ---- 3 levels. Operand-swapped MFMA: Aop = AT rows (u), Bop = h rows (m).
  // D[i=u_local][j=m_local]: col = l16 = m_local, rows = quad*4+r = u_local.
#pragma unroll
  for (int l = 0; l < 3; l++) {
    const ushort_t* A = AT + l * (DD * DD);

    // batch-preload ALL weight frags for this level (32 x 16B -> deep vmcnt queue)
    short8 wf[4][8];
#pragma unroll
    for (int nt = 0; nt < 4; nt++)
#pragma unroll
      for (int ks = 0; ks < 8; ks++)
        wf[nt][ks] = *(const short8*)&A[(wave * 64 + nt * 16 + l16) * 256 + ks * 32 + quad * 8];

    floatx4 acc[4][4];
#pragma unroll
    for (int mt = 0; mt < 4; mt++)
#pragma unroll
      for (int nt = 0; nt < 4; nt++) acc[mt][nt] = zero;

#pragma unroll
    for (int ks = 0; ks < 8; ks++) {
      const int kb = ks * 32 + quad * 8;
      short8 bf[4];
#pragma unroll
      for (int mt = 0; mt < 4; mt++)   // Bop: h[m0+l16][kb..kb+7], ds_read_b128
        bf[mt] = *(const short8*)&hbuf[(mt * 16 + l16) * HSTRIDE + kb];
#pragma unroll
      for (int mt = 0; mt < 4; mt++)
#pragma unroll
        for (int nt = 0; nt < 4; nt++)
          acc[mt][nt] = __builtin_amdgcn_mfma_f32_16x16x32_bf16(wf[nt][ks], bf[mt], acc[mt][nt], 0, 0, 0);
    }
    __syncthreads();  // all hbuf reads done before overwrite

    // epilogue: lane holds 4 consecutive u (cols) for row m = mt*16+l16 -> b64 writes
#pragma unroll
    for (int nt = 0; nt < 4; nt++) {
      float4 bv = *(const float4*)&bias[(l * GG + wave) * UU + nt * 16 + quad * 4];
#pragma unroll
      for (int mt = 0; mt < 4; mt++) {
        ushort4v hv;
        hv.x = f2bf(fast_tanh(acc[mt][nt][0] + bv.x));
        hv.y = f2bf(fast_tanh(acc[mt][nt][1] + bv.y));
        hv.z = f2bf(fast_tanh(acc[mt][nt][2] + bv.z));
        hv.w = f2bf(fast_tanh(acc[mt][nt][3] + bv.w));
        *(ushort4v*)&hbuf[(mt * 16 + l16) * HSTRIDE + wave * 64 + nt * 16 + quad * 4] = hv;
      }
    }
    __syncthreads();
  }

  // ---- final: D[i=o][j=row_local], Aop = WoT[o][k], Bop = h[row][k] ----
  short8 wof[8];
#pragma unroll
  for (int ks = 0; ks < 8; ks++)
    wof[ks] = *(const short8*)&WoT[l16 * 256 + ks * 32 + quad * 8];

  floatx4 accf = zero;
#pragma unroll
  for (int ks = 0; ks < 8; ks++) {
    short8 bf = *(const short8*)&hbuf[(wave * 16 + l16) * HSTRIDE + ks * 32 + quad * 8];
    accf = __builtin_amdgcn_mfma_f32_16x16x32_bf16(wof[ks], bf, accf, 0, 0, 0);
  }

  // lane holds out[row0 + wave*16 + l16][quad*4 .. quad*4+3]
  const long obase = (row0 + wave * 16 + l16) * OUTN;
  if (quad < 2) {
    float2 p0 = {accf[0] + bout[quad * 4 + 0], accf[1] + bout[quad * 4 + 1]};
    float2 p1 = {accf[2] + bout[quad * 4 + 2], accf[3] + bout[quad * 4 + 3]};
    *(float2*)&out[obase + quad * 4]     = p0;
    *(float2*)&out[obase + quad * 4 + 2] = p1;
  } else if (quad == 2) {
    float2 p0 = {accf[0] + bout[8], accf[1] + bout[9]};
    *(float2*)&out[obase + 8] = p0;
  }
}

extern "C" void kernel_launch(void* const* d_in, const int* in_sizes, int n_in,
                              void* d_out, int out_size, void* d_ws, size_t ws_size,
                              hipStream_t stream) {
  const float* x    = (const float*)d_in[0];   // (131072, 256) fp32
  const int*   idx  = (const int*)d_in[1];     // (3, 4, 128) int32
  const float* W    = (const float*)d_in[2];   // (3, 4, 128, 64) fp32
  const float* b    = (const float*)d_in[3];   // (3, 4, 64) fp32
  const float* Wout = (const float*)d_in[4];   // (256, 10) fp32
  const float* bout = (const float*)d_in[5];   // (10,) fp32
  float* out = (float*)d_out;                  // (131072, 10) fp32

  ushort_t* AT  = (ushort_t*)d_ws;             // 3*256*256 bf16
  ushort_t* WoT = AT + LL * DD * DD;           // 16*256 bf16

  prep_kernel<<<LL * DD + 16, 256, 0, stream>>>(idx, W, Wout, AT, WoT);
  fused_kernel<<<2048, 256, 0, stream>>>(x, b, bout, AT, WoT, out);
}

// Round 3
// 286.505 us; speedup vs baseline: 1.1281x; 1.0401x over previous
//
#include <hip/hip_runtime.h>

typedef unsigned short ushort_t;
typedef __attribute__((ext_vector_type(8))) short short8;
typedef __attribute__((ext_vector_type(4))) float floatx4;
typedef __attribute__((ext_vector_type(4))) unsigned short ushort4v;

#define DD 256
#define LL 3
#define GG 4
#define KK 128
#define UU 64
#define OUTN 10
#define HSTRIDE 264   // 256 + 8 bf16 pad; 528B row stride -> conflict-free b128 reads

__device__ __forceinline__ ushort_t f2bf(float f) {
  unsigned u = __builtin_bit_cast(unsigned, f);
  u = (u + 0x7FFFu + ((u >> 16) & 1u)) >> 16;  // RNE; inputs finite
  return (ushort_t)u;
}

// tanh(x) = 1 - 2/(e^{2x}+1); branch-free, exact at overflow
__device__ __forceinline__ float fast_tanh(float x) {
  float e = __builtin_amdgcn_exp2f(x * 2.885390081777927f);
  return __builtin_fmaf(-2.0f, __builtin_amdgcn_rcpf(e + 1.0f), 1.0f);
}

// AT[l][n][k] = sum_{j: idx[l,g,j]==k} W[l,g,j,u]  (n = g*64+u), bf16.
// WoT[n][k] = W_out[k][n] (n<10 else 0), 16x256 bf16.
__global__ __launch_bounds__(256) void prep_kernel(
    const int* __restrict__ idx, const float* __restrict__ W,
    const float* __restrict__ Wout, ushort_t* __restrict__ AT,
    ushort_t* __restrict__ WoT) {
  int b = blockIdx.x;
  int t = threadIdx.x;
  if (b < LL * DD) {
    int l = b >> 8, n = b & 255, g = n >> 6, u = n & 63;
    __shared__ int sidx[KK];
    __shared__ float sw[KK];
    if (t < KK) {
      sidx[t] = idx[(l * GG + g) * KK + t];
      sw[t]   = W[((size_t)((l * GG + g) * KK + t)) * UU + u];
    }
    __syncthreads();
    float s = 0.f;
#pragma unroll 8
    for (int j = 0; j < KK; j++) s += (sidx[j] == t) ? sw[j] : 0.f;
    AT[(b << 8) | t] = f2bf(s);
  } else {
    int e2 = (b - LL * DD) * 256 + t;
    int n = e2 >> 8, k = e2 & 255;
    WoT[e2] = (n < OUTN) ? f2bf(Wout[k * OUTN + n]) : (ushort_t)0;
  }
}

// One level: staggered-prefetch MFMA pipeline + tanh epilogue.
// Ab: this level's weight base (pre-offset to row l16 of this wave's group, col quad*8).
// PF: statement executed after the MFMA loop (prefetch for the NEXT stage).
#define RUN_LEVEL(Ab, PF, BPTR)                                                \
  {                                                                            \
    const ushort_t* hsrc = hbuf + l16 * HSTRIDE + quad * 8;                    \
    short8 wf[8][4];                                                           \
    _Pragma("unroll") for (int nt = 0; nt < 4; nt++) {                         \
      wf[0][nt] = pw0[nt];                                                     \
      wf[1][nt] = pw1[nt];                                                     \
    }                                                                          \
    short8 bf[8][4];                                                           \
    _Pragma("unroll") for (int mt = 0; mt < 4; mt++)                           \
      bf[0][mt] = *(const short8*)&hsrc[mt * 16 * HSTRIDE];                    \
    floatx4 acc[4][4];                                                         \
    _Pragma("unroll") for (int mt = 0; mt < 4; mt++)                           \
      _Pragma("unroll") for (int nt = 0; nt < 4; nt++) acc[mt][nt] = zero;     \
    _Pragma("unroll") for (int ks = 0; ks < 8; ks++) {                         \
      if (ks + 2 < 8) {                                                        \
        _Pragma("unroll") for (int nt = 0; nt < 4; nt++)                       \
          wf[ks + 2][nt] = *(const short8*)&(Ab)[nt * 4096 + (ks + 2) * 32];   \
      }                                                                        \
      if (ks + 1 < 8) {                                                        \
        _Pragma("unroll") for (int mt = 0; mt < 4; mt++)                       \
          bf[ks + 1][mt] =                                                     \
              *(const short8*)&hsrc[mt * 16 * HSTRIDE + (ks + 1) * 32];        \
      }                                                                        \
      _Pragma("unroll") for (int mt = 0; mt < 4; mt++)                         \
        _Pragma("unroll") for (int nt = 0; nt < 4; nt++)                       \
          acc[mt][nt] = __builtin_amdgcn_mfma_f32_16x16x32_bf16(               \
              wf[ks][nt], bf[ks][mt], acc[mt][nt], 0, 0, 0);                   \
    }                                                                          \
    PF;                                                                        \
    __syncthreads(); /* all hbuf reads done before overwrite */                \
    _Pragma("unroll") for (int nt = 0; nt < 4; nt++) {                         \
      float4 bv = *(const float4*)&(BPTR)[nt * 16 + quad * 4];                 \
      _Pragma("unroll") for (int mt = 0; mt < 4; mt++) {                       \
        ushort4v hv;                                                           \
        hv.x = f2bf(fast_tanh(acc[mt][nt][0] + bv.x));                         \
        hv.y = f2bf(fast_tanh(acc[mt][nt][1] + bv.y));                         \
        hv.z = f2bf(fast_tanh(acc[mt][nt][2] + bv.z));                         \
        hv.w = f2bf(fast_tanh(acc[mt][nt][3] + bv.w));                         \
        *(ushort4v*)&hbuf[(mt * 16 + l16) * HSTRIDE + wave * 64 + nt * 16 +    \
                          quad * 4] = hv;                                      \
      }                                                                        \
    }                                                                          \
    __syncthreads();                                                           \
  }

#define PF_NEXT(Anext)                                                         \
  {                                                                            \
    _Pragma("unroll") for (int nt = 0; nt < 4; nt++)                           \
        pw0[nt] = *(const short8*)&(Anext)[nt * 4096];                         \
    _Pragma("unroll") for (int nt = 0; nt < 4; nt++)                           \
        pw1[nt] = *(const short8*)&(Anext)[nt * 4096 + 32];                    \
  }

#define PF_WOUT                                                                \
  {                                                                            \
    _Pragma("unroll") for (int ks = 0; ks < 8; ks++)                           \
        wof[ks] = *(const short8*)&WoT[l16 * 256 + ks * 32 + quad * 8];        \
  }

__global__ __launch_bounds__(256, 2) void fused_kernel(
    const float* __restrict__ x, const float* __restrict__ bias,
    const float* __restrict__ bout, const ushort_t* __restrict__ AT,
    const ushort_t* __restrict__ WoT, float* __restrict__ out) {
  __shared__ ushort_t hbuf[64 * HSTRIDE];  // 33792 B

  const int tid  = threadIdx.x;
  const int wave = tid >> 6;     // wave == group g
  const int lane = tid & 63;
  const int quad = lane >> 4;
  const int l16  = lane & 15;
  const long row0 = (long)blockIdx.x * 64;
  const floatx4 zero = {0.f, 0.f, 0.f, 0.f};

  // per-wave weight bases: row = wave*64 (+ nt*16) + l16, col offset quad*8
  const ushort_t* A0 = AT + (wave * 64 + l16) * 256 + quad * 8;
  const ushort_t* A1 = A0 + 65536;
  const ushort_t* A2 = A0 + 131072;

  short8 pw0[4], pw1[4], wof[8];
  PF_NEXT(A0);  // level-0 chunks 0,1: hide under x staging

  // ---- stage x tile (64 x 256 fp32) -> bf16 LDS ----
  const float4* xv = (const float4*)(x + row0 * DD);
#pragma unroll
  for (int i = 0; i < 16; i++) {
    int f  = tid + i * 256;
    int r  = f >> 6;
    int c4 = f & 63;
    float4 v = xv[r * 64 + c4];
    ushort4v uv;
    uv.x = f2bf(v.x); uv.y = f2bf(v.y); uv.z = f2bf(v.z); uv.w = f2bf(v.w);
    *(ushort4v*)&hbuf[r * HSTRIDE + c4 * 4] = uv;
  }
  __syncthreads();

  const float* b0 = bias + (0 * GG + wave) * UU;
  const float* b1 = bias + (1 * GG + wave) * UU;
  const float* b2 = bias + (2 * GG + wave) * UU;

  RUN_LEVEL(A0, PF_NEXT(A1), b0);
  RUN_LEVEL(A1, PF_NEXT(A2), b1);
  RUN_LEVEL(A2, PF_WOUT,     b2);

  // ---- final: Aop = WoT rows (o), Bop = h rows ----
  floatx4 accf = zero;
#pragma unroll
  for (int ks = 0; ks < 8; ks++) {
    short8 bfr = *(const short8*)&hbuf[(wave * 16 + l16) * HSTRIDE + ks * 32 + quad * 8];
    accf = __builtin_amdgcn_mfma_f32_16x16x32_bf16(wof[ks], bfr, accf, 0, 0, 0);
  }

  const long obase = (row0 + wave * 16 + l16) * OUTN;
  if (quad < 2) {
    float2 p0 = {accf[0] + bout[quad * 4 + 0], accf[1] + bout[quad * 4 + 1]};
    float2 p1 = {accf[2] + bout[quad * 4 + 2], accf[3] + bout[quad * 4 + 3]};
    *(float2*)&out[obase + quad * 4]     = p0;
    *(float2*)&out[obase + quad * 4 + 2] = p1;
  } else if (quad == 2) {
    float2 p0 = {accf[0] + bout[8], accf[1] + bout[9]};
    *(float2*)&out[obase + 8] = p0;
  }
}

extern "C" void kernel_launch(void* const* d_in, const int* in_sizes, int n_in,
                              void* d_out, int out_size, void* d_ws, size_t ws_size,
                              hipStream_t stream) {
  const float* x    = (const float*)d_in[0];   // (131072, 256) fp32
  const int*   idx  = (const int*)d_in[1];     // (3, 4, 128) int32
  const float* W    = (const float*)d_in[2];   // (3, 4, 128, 64) fp32
  const float* b    = (const float*)d_in[3];   // (3, 4, 64) fp32
  const float* Wout = (const float*)d_in[4];   // (256, 10) fp32
  const float* bout = (const float*)d_in[5];   // (10,) fp32
  float* out = (float*)d_out;                  // (131072, 10) fp32

  ushort_t* AT  = (ushort_t*)d_ws;             // 3*256*256 bf16
  ushort_t* WoT = AT + LL * DD * DD;           // 16*256 bf16

  prep_kernel<<<LL * DD + 16, 256, 0, stream>>>(idx, W, Wout, AT, WoT);
  fused_kernel<<<2048, 256, 0, stream>>>(x, b, bout, AT, WoT, out);
}

// Round 4
// 271.099 us; speedup vs baseline: 1.1922x; 1.0568x over previous
//
#include <hip/hip_runtime.h>

typedef unsigned short ushort_t;
typedef __attribute__((ext_vector_type(8))) short short8;
typedef __attribute__((ext_vector_type(4))) float floatx4;

#define DD 256
#define LL 3
#define GG 4
#define KK 128
#define UU 64
#define OUTN 10
#define HSTRIDE 264   // 256 + 8 bf16 pad; 528B row stride
#define MROWS 128     // rows per block

__device__ __forceinline__ ushort_t f2bf(float f) {
  unsigned u = __builtin_bit_cast(unsigned, f);
  u = (u + 0x7FFFu + ((u >> 16) & 1u)) >> 16;
  return (ushort_t)u;
}

// pack two f32 -> two bf16 (round-half-up on magnitude): 2 adds + 1 v_perm_b32
__device__ __forceinline__ unsigned pack_bf2(float lo, float hi) {
  unsigned a = __builtin_bit_cast(unsigned, hi) + 0x8000u;
  unsigned b = __builtin_bit_cast(unsigned, lo) + 0x8000u;
  return __builtin_amdgcn_perm(a, b, 0x07060302u);  // (hi16(a)<<16)|hi16(b)
}

// tanh(x) = 1 - 2/(e^{2x}+1); branch-free, exact at overflow
__device__ __forceinline__ float fast_tanh(float x) {
  float e = __builtin_amdgcn_exp2f(x * 2.885390081777927f);
  return __builtin_fmaf(-2.0f, __builtin_amdgcn_rcpf(e + 1.0f), 1.0f);
}

// AT[l][n][k] = sum_{j: idx[l,g,j]==k} W[l,g,j,u]  (n = g*64+u), bf16.
// WoT[n][k] = W_out[k][n] (n<10 else 0), 16x256 bf16.
__global__ __launch_bounds__(256) void prep_kernel(
    const int* __restrict__ idx, const float* __restrict__ W,
    const float* __restrict__ Wout, ushort_t* __restrict__ AT,
    ushort_t* __restrict__ WoT) {
  int b = blockIdx.x;
  int t = threadIdx.x;
  if (b < LL * DD) {
    int l = b >> 8, n = b & 255, g = n >> 6, u = n & 63;
    __shared__ int sidx[KK];
    __shared__ float sw[KK];
    if (t < KK) {
      sidx[t] = idx[(l * GG + g) * KK + t];
      sw[t]   = W[((size_t)((l * GG + g) * KK + t)) * UU + u];
    }
    __syncthreads();
    float s = 0.f;
#pragma unroll 8
    for (int j = 0; j < KK; j++) s += (sidx[j] == t) ? sw[j] : 0.f;
    AT[(b << 8) | t] = f2bf(s);
  } else {
    int e2 = (b - LL * DD) * 256 + t;
    int n = e2 >> 8, k = e2 & 255;
    WoT[e2] = (n < OUTN) ? f2bf(Wout[k * OUTN + n]) : (ushort_t)0;
  }
}

__global__ __launch_bounds__(256, 2) void fused_kernel(
    const float* __restrict__ x, const float* __restrict__ bias,
    const float* __restrict__ bout, const ushort_t* __restrict__ AT,
    const ushort_t* __restrict__ WoT, float* __restrict__ out) {
  __shared__ ushort_t hbuf[MROWS * HSTRIDE];  // 67584 B -> 2 blocks/CU

  const int tid  = threadIdx.x;
  const int wave = tid >> 6;     // wave == group g (N-split)
  const int lane = tid & 63;
  const int quad = lane >> 4;
  const int l16  = lane & 15;
  const long row0 = (long)blockIdx.x * MROWS;

  // ---- stage x tile (128 x 256 fp32) -> bf16 LDS ----
  const float4* xv = (const float4*)(x + row0 * DD);
#pragma unroll
  for (int i = 0; i < 32; i++) {
    int f  = tid + i * 256;      // 0..8191 float4s, 64 per row
    int r  = f >> 6;
    int c4 = f & 63;
    float4 v = xv[r * 64 + c4];
    uint2 w;
    w.x = pack_bf2(v.x, v.y);
    w.y = pack_bf2(v.z, v.w);
    *(uint2*)&hbuf[r * HSTRIDE + c4 * 4] = w;   // 8B aligned
  }
  __syncthreads();

  // ---- 3 levels. Operand-swap: Aop = AT rows (u), Bop = h rows (m).
  // D: col=l16 -> m_local, row=quad*4+r -> u_local. Bias folded into acc init.
#pragma unroll 1
  for (int l = 0; l < 3; l++) {
    const ushort_t* Ab = AT + l * (DD * DD) + (wave * UU + l16) * DD + quad * 8;
    const ushort_t* hsrc = hbuf + l16 * HSTRIDE + quad * 8;

    floatx4 acc[8][4];
#pragma unroll
    for (int nt = 0; nt < 4; nt++) {
      float4 bv = *(const float4*)&bias[(l * GG + wave) * UU + nt * 16 + quad * 4];
      floatx4 ini = {bv.x, bv.y, bv.z, bv.w};
#pragma unroll
      for (int mt = 0; mt < 8; mt++) acc[mt][nt] = ini;
    }

    short8 wf[4], wfn[4];
#pragma unroll
    for (int nt = 0; nt < 4; nt++) wf[nt] = *(const short8*)&Ab[nt * 16 * DD];

#pragma unroll
    for (int ks = 0; ks < 8; ks++) {
      if (ks < 7) {
#pragma unroll
        for (int nt = 0; nt < 4; nt++)
          wfn[nt] = *(const short8*)&Ab[nt * 16 * DD + (ks + 1) * 32];
      }
      short8 bf[8];
#pragma unroll
      for (int mt = 0; mt < 8; mt++)
        bf[mt] = *(const short8*)&hsrc[mt * 16 * HSTRIDE + ks * 32];
#pragma unroll
      for (int mt = 0; mt < 8; mt++)
#pragma unroll
        for (int nt = 0; nt < 4; nt++)
          acc[mt][nt] = __builtin_amdgcn_mfma_f32_16x16x32_bf16(wf[nt], bf[mt], acc[mt][nt], 0, 0, 0);
#pragma unroll
      for (int nt = 0; nt < 4; nt++) wf[nt] = wfn[nt];
    }
    __syncthreads();  // all hbuf reads done before overwrite

    // epilogue: lane holds 4 consecutive u for row m = mt*16+l16 -> 8B writes
#pragma unroll
    for (int nt = 0; nt < 4; nt++) {
#pragma unroll
      for (int mt = 0; mt < 8; mt++) {
        uint2 w;
        w.x = pack_bf2(fast_tanh(acc[mt][nt][0]), fast_tanh(acc[mt][nt][1]));
        w.y = pack_bf2(fast_tanh(acc[mt][nt][2]), fast_tanh(acc[mt][nt][3]));
        *(uint2*)&hbuf[(mt * 16 + l16) * HSTRIDE + wave * UU + nt * 16 + quad * 4] = w;
      }
    }
    __syncthreads();
  }

  // ---- final: Aop = WoT rows (o), Bop = h rows; 2 M-subtiles per wave ----
  short8 wof[8];
#pragma unroll
  for (int ks = 0; ks < 8; ks++)
    wof[ks] = *(const short8*)&WoT[l16 * DD + ks * 32 + quad * 8];

  const floatx4 zero = {0.f, 0.f, 0.f, 0.f};
#pragma unroll
  for (int s = 0; s < 2; s++) {
    floatx4 accf = zero;
#pragma unroll
    for (int ks = 0; ks < 8; ks++) {
      short8 bfr = *(const short8*)&hbuf[(wave * 32 + s * 16 + l16) * HSTRIDE + ks * 32 + quad * 8];
      accf = __builtin_amdgcn_mfma_f32_16x16x32_bf16(wof[ks], bfr, accf, 0, 0, 0);
    }
    const long obase = (row0 + wave * 32 + s * 16 + l16) * OUTN;
    if (quad < 2) {
      float4 p = {accf[0] + bout[quad * 4 + 0], accf[1] + bout[quad * 4 + 1],
                  accf[2] + bout[quad * 4 + 2], accf[3] + bout[quad * 4 + 3]};
      *(float4*)&out[obase + quad * 4] = p;   // 8B-aligned dwordx4 ok on gfx9
    } else if (quad == 2) {
      float2 p = {accf[0] + bout[8], accf[1] + bout[9]};
      *(float2*)&out[obase + 8] = p;
    }
  }
}

extern "C" void kernel_launch(void* const* d_in, const int* in_sizes, int n_in,
                              void* d_out, int out_size, void* d_ws, size_t ws_size,
                              hipStream_t stream) {
  const float* x    = (const float*)d_in[0];   // (131072, 256) fp32
  const int*   idx  = (const int*)d_in[1];     // (3, 4, 128) int32
  const float* W    = (const float*)d_in[2];   // (3, 4, 128, 64) fp32
  const float* b    = (const float*)d_in[3];   // (3, 4, 64) fp32
  const float* Wout = (const float*)d_in[4];   // (256, 10) fp32
  const float* bout = (const float*)d_in[5];   // (10,) fp32
  float* out = (float*)d_out;                  // (131072, 10) fp32

  ushort_t* AT  = (ushort_t*)d_ws;             // 3*256*256 bf16
  ushort_t* WoT = AT + LL * DD * DD;           // 16*256 bf16

  prep_kernel<<<LL * DD + 16, 256, 0, stream>>>(idx, W, Wout, AT, WoT);
  fused_kernel<<<131072 / MROWS, 256, 0, stream>>>(x, b, bout, AT, WoT, out);
}

// Round 5
// 258.208 us; speedup vs baseline: 1.2518x; 1.0499x over previous
//
#include <hip/hip_runtime.h>

typedef unsigned short ushort_t;
typedef __attribute__((ext_vector_type(8))) short short8;
typedef __attribute__((ext_vector_type(4))) float floatx4;

#define DD 256
#define LL 3
#define GG 4
#define KK 128
#define UU 64
#define OUTN 10
#define HSTRIDE 264   // 256 + 8 bf16 pad; 528B row stride
#define MROWS 128     // rows per block
#define NT 2          // 16-col tiles per wave (8 waves x 32 cols = 256)

__device__ __forceinline__ ushort_t f2bf(float f) {
  unsigned u = __builtin_bit_cast(unsigned, f);
  u = (u + 0x7FFFu + ((u >> 16) & 1u)) >> 16;
  return (ushort_t)u;
}

// pack two f32 -> two bf16: 2 adds + 1 v_perm_b32
__device__ __forceinline__ unsigned pack_bf2(float lo, float hi) {
  unsigned a = __builtin_bit_cast(unsigned, hi) + 0x8000u;
  unsigned b = __builtin_bit_cast(unsigned, lo) + 0x8000u;
  return __builtin_amdgcn_perm(a, b, 0x07060302u);
}

// tanh(x) = 1 - 2/(e^{2x}+1); branch-free, exact at overflow
__device__ __forceinline__ float fast_tanh(float x) {
  float e = __builtin_amdgcn_exp2f(x * 2.885390081777927f);
  return __builtin_fmaf(-2.0f, __builtin_amdgcn_rcpf(e + 1.0f), 1.0f);
}

// AT[l][n][k] = sum_{j: idx[l,g,j]==k} W[l,g,j,u]  (n = g*64+u), bf16.
// WoT[n][k] = W_out[k][n] (n<10 else 0), 16x256 bf16.
__global__ __launch_bounds__(256) void prep_kernel(
    const int* __restrict__ idx, const float* __restrict__ W,
    const float* __restrict__ Wout, ushort_t* __restrict__ AT,
    ushort_t* __restrict__ WoT) {
  int b = blockIdx.x;
  int t = threadIdx.x;
  if (b < LL * DD) {
    int l = b >> 8, n = b & 255, g = n >> 6, u = n & 63;
    __shared__ int sidx[KK];
    __shared__ float sw[KK];
    if (t < KK) {
      sidx[t] = idx[(l * GG + g) * KK + t];
      sw[t]   = W[((size_t)((l * GG + g) * KK + t)) * UU + u];
    }
    __syncthreads();
    float s = 0.f;
#pragma unroll 8
    for (int j = 0; j < KK; j++) s += (sidx[j] == t) ? sw[j] : 0.f;
    AT[(b << 8) | t] = f2bf(s);
  } else {
    int e2 = (b - LL * DD) * 256 + t;
    int n = e2 >> 8, k = e2 & 255;
    WoT[e2] = (n < OUTN) ? f2bf(Wout[k * OUTN + n]) : (ushort_t)0;
  }
}

__global__ __launch_bounds__(512, 4) void fused_kernel(
    const float* __restrict__ x, const float* __restrict__ bias,
    const float* __restrict__ bout, const ushort_t* __restrict__ AT,
    const ushort_t* __restrict__ WoT, float* __restrict__ out) {
  __shared__ ushort_t hbuf[MROWS * HSTRIDE];  // 67584 B -> 2 blocks/CU

  const int tid  = threadIdx.x;
  const int wave = tid >> 6;     // 0..7: N-cols [wave*32, wave*32+32)
  const int lane = tid & 63;
  const int quad = lane >> 4;
  const int l16  = lane & 15;
  const long row0 = (long)blockIdx.x * MROWS;

  // ---- stage x tile (128 x 256 fp32) -> bf16 LDS ----
  const float4* xv = (const float4*)(x + row0 * DD);
#pragma unroll
  for (int i = 0; i < 16; i++) {
    int f  = tid + i * 512;      // 0..8191 float4s, 64 per row
    int r  = f >> 6;
    int c4 = f & 63;
    float4 v = xv[r * 64 + c4];
    uint2 w;
    w.x = pack_bf2(v.x, v.y);
    w.y = pack_bf2(v.z, v.w);
    *(uint2*)&hbuf[r * HSTRIDE + c4 * 4] = w;
  }
  __syncthreads();

  // ---- 3 levels. Operand-swap: Aop = AT rows (u), Bop = h rows (m).
  // D: col=l16 -> m_local, row=quad*4+r -> u_local. Bias folded into acc init.
#pragma unroll 1
  for (int l = 0; l < 3; l++) {
    const ushort_t* Ab = AT + l * (DD * DD) + (wave * 32 + l16) * DD + quad * 8;
    const ushort_t* hsrc = hbuf + l16 * HSTRIDE + quad * 8;

    floatx4 acc[8][NT];
#pragma unroll
    for (int nt = 0; nt < NT; nt++) {
      float4 bv = *(const float4*)&bias[l * DD + wave * 32 + nt * 16 + quad * 4];
      floatx4 ini = {bv.x, bv.y, bv.z, bv.w};
#pragma unroll
      for (int mt = 0; mt < 8; mt++) acc[mt][nt] = ini;
    }

    short8 wf[NT], wfn[NT];
#pragma unroll
    for (int nt = 0; nt < NT; nt++) wf[nt] = *(const short8*)&Ab[nt * 16 * DD];

#pragma unroll
    for (int ks = 0; ks < 8; ks++) {
      if (ks < 7) {
#pragma unroll
        for (int nt = 0; nt < NT; nt++)
          wfn[nt] = *(const short8*)&Ab[nt * 16 * DD + (ks + 1) * 32];
      }
      // hand-staggered LDS reads: only 2 bf frags live at once
      short8 bfc = *(const short8*)&hsrc[0 * 16 * HSTRIDE + ks * 32];
#pragma unroll
      for (int mt = 0; mt < 8; mt++) {
        short8 bfn;
        if (mt < 7) bfn = *(const short8*)&hsrc[(mt + 1) * 16 * HSTRIDE + ks * 32];
        acc[mt][0] = __builtin_amdgcn_mfma_f32_16x16x32_bf16(wf[0], bfc, acc[mt][0], 0, 0, 0);
        acc[mt][1] = __builtin_amdgcn_mfma_f32_16x16x32_bf16(wf[1], bfc, acc[mt][1], 0, 0, 0);
        bfc = bfn;
      }
#pragma unroll
      for (int nt = 0; nt < NT; nt++) wf[nt] = wfn[nt];
    }
    __syncthreads();  // all hbuf reads done before overwrite

    // epilogue: lane holds 4 consecutive u for row m = mt*16+l16 -> 8B writes
#pragma unroll
    for (int nt = 0; nt < NT; nt++) {
#pragma unroll
      for (int mt = 0; mt < 8; mt++) {
        uint2 w;
        w.x = pack_bf2(fast_tanh(acc[mt][nt][0]), fast_tanh(acc[mt][nt][1]));
        w.y = pack_bf2(fast_tanh(acc[mt][nt][2]), fast_tanh(acc[mt][nt][3]));
        *(uint2*)&hbuf[(mt * 16 + l16) * HSTRIDE + wave * 32 + nt * 16 + quad * 4] = w;
      }
    }
    __syncthreads();
  }

  // ---- final: Aop = WoT rows (o), Bop = h rows; 16 rows per wave ----
  short8 wof[8];
#pragma unroll
  for (int ks = 0; ks < 8; ks++)
    wof[ks] = *(const short8*)&WoT[l16 * DD + ks * 32 + quad * 8];

  floatx4 accf = {0.f, 0.f, 0.f, 0.f};
#pragma unroll
  for (int ks = 0; ks < 8; ks++) {
    short8 bfr = *(const short8*)&hbuf[(wave * 16 + l16) * HSTRIDE + ks * 32 + quad * 8];
    accf = __builtin_amdgcn_mfma_f32_16x16x32_bf16(wof[ks], bfr, accf, 0, 0, 0);
  }
  const long obase = (row0 + wave * 16 + l16) * OUTN;
  if (quad < 2) {
    float4 p = {accf[0] + bout[quad * 4 + 0], accf[1] + bout[quad * 4 + 1],
                accf[2] + bout[quad * 4 + 2], accf[3] + bout[quad * 4 + 3]};
    *(float4*)&out[obase + quad * 4] = p;
  } else if (quad == 2) {
    float2 p = {accf[0] + bout[8], accf[1] + bout[9]};
    *(float2*)&out[obase + 8] = p;
  }
}

extern "C" void kernel_launch(void* const* d_in, const int* in_sizes, int n_in,
                              void* d_out, int out_size, void* d_ws, size_t ws_size,
                              hipStream_t stream) {
  const float* x    = (const float*)d_in[0];   // (131072, 256) fp32
  const int*   idx  = (const int*)d_in[1];     // (3, 4, 128) int32
  const float* W    = (const float*)d_in[2];   // (3, 4, 128, 64) fp32
  const float* b    = (const float*)d_in[3];   // (3, 4, 64) fp32
  const float* Wout = (const float*)d_in[4];   // (256, 10) fp32
  const float* bout = (const float*)d_in[5];   // (10,) fp32
  float* out = (float*)d_out;                  // (131072, 10) fp32

  ushort_t* AT  = (ushort_t*)d_ws;             // 3*256*256 bf16
  ushort_t* WoT = AT + LL * DD * DD;           // 16*256 bf16

  prep_kernel<<<LL * DD + 16, 256, 0, stream>>>(idx, W, Wout, AT, WoT);
  fused_kernel<<<131072 / MROWS, 512, 0, stream>>>(x, b, bout, AT, WoT, out);
}